// Round 1
// baseline (691.351 us; speedup 1.0000x reference)
//
#include <hip/hip_runtime.h>

// Problem constants (fixed by setup_inputs in the reference)
constexpr int FRAME   = 1024;
constexpr int HOP     = 512;
constexpr int BATCH   = 64;
constexpr int SAMPLES = 1 << 20;
constexpr int NSEG    = SAMPLES / HOP - FRAME / HOP + 1;   // 2047
constexpr int F4      = FRAME / 4;      // 256 float4 per frame
constexpr int H4      = HOP / 4;        // 128 float4 per hop
constexpr int S4      = SAMPLES / 4;    // float4 per batch row

// out[b][s][f] = x[b][s*HOP + f] * W[s][f]
// One block per (b, s) frame; 256 threads, one float4 each.
__global__ __launch_bounds__(256) void seg_win_kernel(
    const float4* __restrict__ x,
    const float4* __restrict__ win,
    const float4* __restrict__ pre,
    const float4* __restrict__ post,
    float4* __restrict__ out)
{
    const int blk = blockIdx.x;                 // = b * NSEG + s
    const int s   = blk % NSEG;
    const int b   = blk / NSEG;

    // Window row: uniform per block (no divergence inside the wave)
    const float4* __restrict__ w =
        (s == 0) ? pre : (s == NSEG - 1) ? post : win;

    const int f = threadIdx.x;                  // 0..255

    const float4 wv = w[f];                     // L1/L2-resident (3 KB total)
    const float4 xv = x[(size_t)b * S4 + (size_t)s * H4 + f];

    float4 o;
    o.x = xv.x * wv.x;
    o.y = xv.y * wv.y;
    o.z = xv.z * wv.z;
    o.w = xv.w * wv.w;

    out[(size_t)blk * F4 + f] = o;
}

extern "C" void kernel_launch(void* const* d_in, const int* in_sizes, int n_in,
                              void* d_out, int out_size, void* d_ws, size_t ws_size,
                              hipStream_t stream)
{
    // setup_inputs order: x, window, prewindow, postwindow, hop_size, frame_size
    const float4* x    = (const float4*)d_in[0];
    const float4* win  = (const float4*)d_in[1];
    const float4* pre  = (const float4*)d_in[2];
    const float4* post = (const float4*)d_in[3];
    float4* out        = (float4*)d_out;

    dim3 grid(BATCH * NSEG);   // 131008 blocks
    dim3 block(F4);            // 256 threads
    seg_win_kernel<<<grid, block, 0, stream>>>(x, win, pre, post, out);
}

// Round 3
// 671.246 us; speedup vs baseline: 1.0300x; 1.0300x over previous
//
#include <hip/hip_runtime.h>

// Problem constants (fixed by setup_inputs in the reference)
constexpr int FRAME   = 1024;
constexpr int HOP     = 512;
constexpr int BATCH   = 64;
constexpr int SAMPLES = 1 << 20;
constexpr int NSEG    = SAMPLES / HOP - FRAME / HOP + 1;   // 2047
constexpr int F4      = FRAME / 4;      // 256 float4 per frame
constexpr int H4      = HOP / 4;        // 128 float4 per hop
constexpr int S4      = SAMPLES / 4;    // 262144 float4 per batch row

// Native vector type — required for __builtin_nontemporal_*
typedef float f32x4 __attribute__((ext_vector_type(4)));

// Hop-centric: thread t owns one float4 of x and feeds the (at most) two
// frames that contain it. x is read exactly once from HBM.
//   x float4 index j4 = h*H4 + r  (h = hop, r in [0,H4))
//   -> frame s=h,   f4 = r        (if h <= NSEG-1)
//   -> frame s=h-1, f4 = r + H4   (if h >= 1)
__global__ __launch_bounds__(256) void seg_win_hop_kernel(
    const f32x4* __restrict__ x,
    const f32x4* __restrict__ win,
    const f32x4* __restrict__ pre,
    const f32x4* __restrict__ post,
    f32x4* __restrict__ out)
{
    const size_t gid = (size_t)blockIdx.x * 256 + threadIdx.x;  // [0, BATCH*S4)
    const int b  = (int)(gid >> 18);          // gid / S4   (S4 = 2^18)
    const int j4 = (int)(gid & (S4 - 1));     // gid % S4
    const int h  = j4 >> 7;                   // j4 / H4  — wave-uniform
    const int r  = j4 & (H4 - 1);             // j4 % H4

    const f32x4 xv = __builtin_nontemporal_load(&x[gid]);

    const size_t out_row_base = (size_t)b * NSEG;

    // Store 1: first half of frame s = h
    if (h <= NSEG - 1) {
        const int s = h;
        const f32x4* __restrict__ w =
            (s == 0) ? pre : (s == NSEG - 1) ? post : win;
        const f32x4 wv = w[r];
        const f32x4 o = xv * wv;
        __builtin_nontemporal_store(o, &out[(out_row_base + s) * F4 + r]);
    }

    // Store 2: second half of frame s = h - 1
    if (h >= 1) {
        const int s = h - 1;
        const f32x4* __restrict__ w =
            (s == 0) ? pre : (s == NSEG - 1) ? post : win;
        const f32x4 wv = w[r + H4];
        const f32x4 o = xv * wv;
        __builtin_nontemporal_store(o, &out[(out_row_base + s) * F4 + r + H4]);
    }
}

extern "C" void kernel_launch(void* const* d_in, const int* in_sizes, int n_in,
                              void* d_out, int out_size, void* d_ws, size_t ws_size,
                              hipStream_t stream)
{
    // setup_inputs order: x, window, prewindow, postwindow, hop_size, frame_size
    const f32x4* x    = (const f32x4*)d_in[0];
    const f32x4* win  = (const f32x4*)d_in[1];
    const f32x4* pre  = (const f32x4*)d_in[2];
    const f32x4* post = (const f32x4*)d_in[3];
    f32x4* out        = (f32x4*)d_out;

    // BATCH * S4 = 16,777,216 threads -> 65,536 blocks of 256
    dim3 grid((BATCH * (size_t)S4) / 256);
    dim3 block(256);
    seg_win_hop_kernel<<<grid, block, 0, stream>>>(x, win, pre, post, out);
}